// Round 2
// baseline (548.846 us; speedup 1.0000x reference)
//
#include <hip/hip_runtime.h>
#include <hip/hip_bf16.h>

#define BATCH 8
#define NC 2048
#define NF 8192
#define CDIM 256
#define CSKIP 64
#define OUTD 256
#define MTOT (BATCH*NF)   // 65536
#define NCTOT (BATCH*NC)  // 16384

typedef __attribute__((ext_vector_type(8))) short short8;
typedef __attribute__((ext_vector_type(4))) float floatx4;

static __device__ __forceinline__ ushort f2bf(float f) {
    union { float f; unsigned u; } v; v.f = f;
    unsigned r = v.u + 0x7fffu + ((v.u >> 16) & 1u);   // RNE
    return (ushort)(r >> 16);
}

// ---- kernel 1: prep. Segments:
//  seg0: x -> xb bf16        (1048576 thr, 4-wide)
//  seg1: x_skip -> xsb bf16  (1048576 thr, 4-wide)
//  seg2: W1[0:256,:]  -> Bt1a[n][k]  (65536)
//  seg3: W1[256:320,:]-> Bt1b[n][k2] (16384)
//  seg4: W2           -> Bt2[n][k]   (65536)
//  seg5: pos -> pos4 float4          (16384)
#define SEG0 1048576
#define SEG1 1048576
#define SEG2 65536
#define SEG3 16384
#define SEG4 65536
#define SEG5 16384
#define PREP_THREADS (SEG0+SEG1+SEG2+SEG3+SEG4+SEG5)

__global__ __launch_bounds__(256) void prep_kernel(const float* __restrict__ x,
                                                   const float* __restrict__ x_skip,
                                                   const float* __restrict__ W1,
                                                   const float* __restrict__ W2,
                                                   const float* __restrict__ pos,
                                                   ushort* __restrict__ xb,
                                                   ushort* __restrict__ xsb,
                                                   ushort* __restrict__ Bt1a,
                                                   ushort* __restrict__ Bt1b,
                                                   ushort* __restrict__ Bt2,
                                                   float4* __restrict__ pos4) {
    int t = blockIdx.x * 256 + threadIdx.x;
    if (t < SEG0) {
        float4 v = ((const float4*)x)[t];
        ushort4 p; p.x = f2bf(v.x); p.y = f2bf(v.y); p.z = f2bf(v.z); p.w = f2bf(v.w);
        ((ushort4*)xb)[t] = p;
        return;
    }
    t -= SEG0;
    if (t < SEG1) {
        float4 v = ((const float4*)x_skip)[t];
        ushort4 p; p.x = f2bf(v.x); p.y = f2bf(v.y); p.z = f2bf(v.z); p.w = f2bf(v.w);
        ((ushort4*)xsb)[t] = p;
        return;
    }
    t -= SEG1;
    if (t < SEG2) {
        int k = t & 255, n = t >> 8;
        Bt1a[n * 256 + k] = f2bf(W1[k * 256 + n]);
        return;
    }
    t -= SEG2;
    if (t < SEG3) {
        int k2 = t & 63, n = t >> 6;
        Bt1b[n * 64 + k2] = f2bf(W1[(256 + k2) * 256 + n]);
        return;
    }
    t -= SEG3;
    if (t < SEG4) {
        int k = t & 255, n = t >> 8;
        Bt2[n * 256 + k] = f2bf(W2[k * 256 + n]);
        return;
    }
    t -= SEG4;
    if (t < SEG5) {
        float4 q;
        q.x = pos[t * 3 + 0]; q.y = pos[t * 3 + 1]; q.z = pos[t * 3 + 2]; q.w = 0.f;
        pos4[t] = q;
    }
}

// ---- kernel 2: kNN top-3. 1 thread = 1 fine point; coarse positions via
// wave-uniform float4 global loads (L1 broadcast).
__global__ __launch_bounds__(256) void knn_kernel(const float4* __restrict__ pos4,
                                                  const float* __restrict__ pos_skip,
                                                  int* __restrict__ idxw,
                                                  float* __restrict__ wgt) {
    int m = blockIdx.x * 256 + threadIdx.x;
    int b = m >> 13;                               // NF = 8192
    const float4* pc = pos4 + b * NC;
    float px = pos_skip[m * 3 + 0];
    float py = pos_skip[m * 3 + 1];
    float pz = pos_skip[m * 3 + 2];

    float d0 = 1e30f, d1 = 1e30f, d2 = 1e30f;
    int i0 = 0, i1 = 0, i2 = 0;
#pragma unroll 4
    for (int j = 0; j < NC; ++j) {
        float4 q = pc[j];
        float dx = px - q.x, dy = py - q.y, dz = pz - q.z;
        float d = dx * dx + dy * dy + dz * dz;
        if (d < d2) {
            if (d < d1) {
                d2 = d1; i2 = i1;
                if (d < d0) { d1 = d0; i1 = i0; d0 = d; i0 = j; }
                else        { d1 = d;  i1 = j; }
            } else { d2 = d; i2 = j; }
        }
    }
    float w0 = 1.0f / fmaxf(d0, 1e-16f);
    float w1 = 1.0f / fmaxf(d1, 1e-16f);
    float w2 = 1.0f / fmaxf(d2, 1e-16f);
    float inv = 1.0f / (w0 + w1 + w2);
    idxw[m * 3 + 0] = b * NC + i0;
    idxw[m * 3 + 1] = b * NC + i1;
    idxw[m * 3 + 2] = b * NC + i2;
    wgt[m * 3 + 0] = w0 * inv;
    wgt[m * 3 + 1] = w1 * inv;
    wgt[m * 3 + 2] = w2 * inv;
}

// ---- kernel 3: G = xb @ Bt1a^T (fp32 out, no bias/relu). 16384 x 256, K=256.
// Wave = 16 rows x 256 cols. Verified 16x16x32 bf16 layouts.
__global__ __launch_bounds__(256) void gemm_G(const ushort* __restrict__ A,
                                              const ushort* __restrict__ Bt,
                                              float* __restrict__ G) {
    int wave = threadIdx.x >> 6, lane = threadIdx.x & 63;
    int m0 = blockIdx.x * 64 + wave * 16;
    int lrow = lane & 15;
    int ko = (lane >> 4) * 8;
    const ushort* arow = A + (size_t)(m0 + lrow) * 256 + ko;
    const ushort* bbase = Bt + (size_t)lrow * 256 + ko;

    floatx4 acc[16];
#pragma unroll
    for (int i = 0; i < 16; ++i) acc[i] = (floatx4){0.f, 0.f, 0.f, 0.f};

    for (int k0 = 0; k0 < 256; k0 += 32) {
        short8 af = *(const short8*)(arow + k0);
#pragma unroll
        for (int nt = 0; nt < 16; ++nt) {
            short8 bf = *(const short8*)(bbase + (size_t)nt * 16 * 256 + k0);
            acc[nt] = __builtin_amdgcn_mfma_f32_16x16x32_bf16(af, bf, acc[nt], 0, 0, 0);
        }
    }
    int rbase = (lane >> 4) * 4;
#pragma unroll
    for (int nt = 0; nt < 16; ++nt) {
        int n = nt * 16 + lrow;
#pragma unroll
        for (int r = 0; r < 4; ++r)
            G[(size_t)(m0 + rbase + r) * 256 + n] = acc[nt][r];
    }
}

// ---- kernel 4: fused  h1 = relu(x_skip@W1b + interp(G) + b1);  out = relu(h1@W2 + b2)
// Block = 4 waves, 64 fine rows. h1 tile bf16 in wave-private LDS (no barrier).
#define LDS_STRIDE 264   // 256 + 8 ushorts: keeps 16B alignment, breaks pow2 banks
__global__ __launch_bounds__(256) void fused_kernel(const ushort* __restrict__ xsb,
                                                    const ushort* __restrict__ Bt1b,
                                                    const float* __restrict__ G,
                                                    const int* __restrict__ idxw,
                                                    const float* __restrict__ wgt,
                                                    const float* __restrict__ b1,
                                                    const ushort* __restrict__ Bt2,
                                                    const float* __restrict__ b2,
                                                    float* __restrict__ out) {
    __shared__ ushort h1t[4][16 * LDS_STRIDE];     // 33 KB
    int wave = threadIdx.x >> 6, lane = threadIdx.x & 63;
    int m0 = blockIdx.x * 64 + wave * 16;
    int lrow = lane & 15;
    int ko = (lane >> 4) * 8;
    int rbase = (lane >> 4) * 4;

    // ---- stage 1: S = x_skip_tile @ W1b^T  (K=64)
    floatx4 acc[16];
#pragma unroll
    for (int i = 0; i < 16; ++i) acc[i] = (floatx4){0.f, 0.f, 0.f, 0.f};
    {
        const ushort* arow = xsb + (size_t)(m0 + lrow) * 64 + ko;
        const ushort* bb = Bt1b + lrow * 64 + ko;
        for (int k0 = 0; k0 < 64; k0 += 32) {
            short8 af = *(const short8*)(arow + k0);
#pragma unroll
            for (int nt = 0; nt < 16; ++nt) {
                short8 bf = *(const short8*)(bb + nt * 16 * 64 + k0);
                acc[nt] = __builtin_amdgcn_mfma_f32_16x16x32_bf16(af, bf, acc[nt], 0, 0, 0);
            }
        }
    }

    // per-lane neighbor idx/weights for its 4 C-layout rows
    int gi[4][3]; float gw[4][3];
#pragma unroll
    for (int r = 0; r < 4; ++r) {
        int row = m0 + rbase + r;
#pragma unroll
        for (int k = 0; k < 3; ++k) {
            gi[r][k] = idxw[row * 3 + k];
            gw[r][k] = wgt[row * 3 + k];
        }
    }

    // ---- stage 2: h1 = relu(S + interp(G) + b1) -> LDS bf16 tile
    ushort* ht = h1t[wave];
#pragma unroll
    for (int nt = 0; nt < 16; ++nt) {
        int n = nt * 16 + lrow;
        float bv = b1[n];
#pragma unroll
        for (int r = 0; r < 4; ++r) {
            float g = gw[r][0] * G[(size_t)gi[r][0] * 256 + n]
                    + gw[r][1] * G[(size_t)gi[r][1] * 256 + n]
                    + gw[r][2] * G[(size_t)gi[r][2] * 256 + n];
            float v = fmaxf(acc[nt][r] + g + bv, 0.f);
            ht[(rbase + r) * LDS_STRIDE + n] = f2bf(v);
        }
    }

    // ---- stage 3: out = relu(h1 @ W2^T + b2)  (K=256), A from own LDS tile
#pragma unroll
    for (int i = 0; i < 16; ++i) acc[i] = (floatx4){0.f, 0.f, 0.f, 0.f};
    {
        const ushort* bb = Bt2 + lrow * 256 + ko;
        const ushort* ar = ht + lrow * LDS_STRIDE + ko;
        for (int k0 = 0; k0 < 256; k0 += 32) {
            short8 af = *(const short8*)(ar + k0);
#pragma unroll
            for (int nt = 0; nt < 16; ++nt) {
                short8 bf = *(const short8*)(bb + nt * 16 * 256 + k0);
                acc[nt] = __builtin_amdgcn_mfma_f32_16x16x32_bf16(af, bf, acc[nt], 0, 0, 0);
            }
        }
    }
#pragma unroll
    for (int nt = 0; nt < 16; ++nt) {
        int n = nt * 16 + lrow;
        float bv = b2[n];
#pragma unroll
        for (int r = 0; r < 4; ++r) {
            float v = fmaxf(acc[nt][r] + bv, 0.f);
            out[(size_t)(m0 + rbase + r) * OUTD + n] = v;
        }
    }
}

// ---- kernel 5: tail outputs (pos_skip copy + batch ids as float)
__global__ __launch_bounds__(256) void tail_kernel(const float* __restrict__ pos_skip,
                                                   float* __restrict__ out) {
    int t = blockIdx.x * 256 + threadIdx.x;
    if (t < MTOT * 3) out[(size_t)MTOT * OUTD + t] = pos_skip[t];
    if (t < MTOT)     out[(size_t)MTOT * OUTD + (size_t)MTOT * 3 + t] = (float)(t >> 13);
}

extern "C" void kernel_launch(void* const* d_in, const int* in_sizes, int n_in,
                              void* d_out, int out_size, void* d_ws, size_t ws_size,
                              hipStream_t stream) {
    const float* x        = (const float*)d_in[0];
    const float* pos      = (const float*)d_in[1];
    const float* x_skip   = (const float*)d_in[3];
    const float* pos_skip = (const float*)d_in[4];
    const float* W1       = (const float*)d_in[6];
    const float* b1       = (const float*)d_in[7];
    const float* W2       = (const float*)d_in[8];
    const float* b2       = (const float*)d_in[9];

    char* ws = (char*)d_ws;
    size_t off = 0;
    int*    idxw = (int*)(ws + off);    off += (size_t)MTOT * 3 * 4;      //  768 KB
    float*  wgt  = (float*)(ws + off);  off += (size_t)MTOT * 3 * 4;      //  768 KB
    ushort* xb   = (ushort*)(ws + off); off += (size_t)NCTOT * 256 * 2;   //    8 MB
    ushort* xsb  = (ushort*)(ws + off); off += (size_t)MTOT * 64 * 2;     //    8 MB
    float*  G    = (float*)(ws + off);  off += (size_t)NCTOT * 256 * 4;   //   16 MB
    ushort* Bt1a = (ushort*)(ws + off); off += (size_t)256 * 256 * 2;     //  128 KB
    ushort* Bt1b = (ushort*)(ws + off); off += (size_t)256 * 64 * 2;      //   32 KB
    ushort* Bt2  = (ushort*)(ws + off); off += (size_t)256 * 256 * 2;     //  128 KB
    float4* pos4 = (float4*)(ws + off); off += (size_t)(NCTOT + 4) * 16;  //  256 KB
    // total ~34 MB (round-1 failure: 77 MB overflowed ws -> corrupted pristine inputs)

    float* out = (float*)d_out;

    prep_kernel<<<(PREP_THREADS + 255) / 256, 256, 0, stream>>>(
        x, x_skip, W1, W2, pos, xb, xsb, Bt1a, Bt1b, Bt2, pos4);
    knn_kernel<<<MTOT / 256, 256, 0, stream>>>(pos4, pos_skip, idxw, wgt);
    gemm_G<<<NCTOT / 64, 256, 0, stream>>>(xb, Bt1a, G);
    fused_kernel<<<MTOT / 64, 256, 0, stream>>>(xsb, Bt1b, G, idxw, wgt, b1, Bt2, b2, out);
    tail_kernel<<<(MTOT * 3 + 255) / 256, 256, 0, stream>>>(pos_skip, out);
}